// Round 15
// baseline (81.226 us; speedup 1.0000x reference)
//
#include <hip/hip_runtime.h>

typedef int   int4v   __attribute__((ext_vector_type(4)));
typedef float float4v __attribute__((ext_vector_type(4)));

#define N_DIM 65536

// Magic-number round-half-even quantization: fma(v, s, 1.5*2^23) leaves
// RNE(v*s) in the low mantissa bits; clamp in the magic domain; the int8
// two's-complement encoding is the low byte.
#define QMAGIC 12582912.0f            // 1.5 * 2^23
#define QHI    12583039.0f            // QMAGIC + 127
#define QLO    12582784.0f            // QMAGIC - 128

__device__ __forceinline__ int clamp16(int s) {
    s = s > 32767 ? 32767 : s;
    s = s < -32768 ? -32768 : s;
    return s;
}

__device__ __forceinline__ unsigned int pack_low_bytes(float f0, float f1,
                                                       float f2, float f3) {
    unsigned int p01 = __builtin_amdgcn_perm(__float_as_uint(f1),
                                             __float_as_uint(f0), 0x00000400u);
    unsigned int p23 = __builtin_amdgcn_perm(__float_as_uint(f3),
                                             __float_as_uint(f2), 0x00000400u);
    return __builtin_amdgcn_perm(p23, p01, 0x05040100u);
}

// x-quant: q = clamp(RNE(x*16), -128, 127), packed 4x int8
__device__ __forceinline__ unsigned int qpack(float4v v) {
    float f0 = fminf(fmaxf(fmaf(v.x, 16.0f, QMAGIC), QLO), QHI);
    float f1 = fminf(fmaxf(fmaf(v.y, 16.0f, QMAGIC), QLO), QHI);
    float f2 = fminf(fmaxf(fmaf(v.z, 16.0f, QMAGIC), QLO), QHI);
    float f3 = fminf(fmaxf(fmaf(v.w, 16.0f, QMAGIC), QLO), QHI);
    return pack_low_bytes(f0, f1, f2, f3);
}

// prob-quant: q = min(RNE(e*qs), 127)  (e,qs >= 0)
__device__ __forceinline__ unsigned int qpack_probs(float e0, float e1,
                                                    float e2, float e3, float qs) {
    float f0 = fminf(fmaf(e0, qs, QMAGIC), QHI);
    float f1 = fminf(fmaf(e1, qs, QMAGIC), QHI);
    float f2 = fminf(fmaf(e2, qs, QMAGIC), QHI);
    float f3 = fminf(fmaf(e3, qs, QMAGIC), QHI);
    return pack_low_bytes(f0, f1, f2, f3);
}

// Raw v_exp_f32 (2^x). Args <= 0; deep-negative underflows to 0 on both sides.
__device__ __forceinline__ float fexp2(float a) {
    float r;
    asm("v_exp_f32 %0, %1" : "=v"(r) : "v"(a));
    return r;
}

// Pre-pass: w1/w2 are int-valued float32 in [-16,15]; pack to int8.
__global__ __launch_bounds__(256) void quant_weights(const float* __restrict__ w1,
                                                     const float* __restrict__ w2,
                                                     unsigned char* __restrict__ w1q,
                                                     unsigned char* __restrict__ w2q) {
    int idx = blockIdx.x * 256 + threadIdx.x;   // 32768 threads, 4 elems each
    const float* src;
    unsigned char* dst;
    int off;
    if (idx < 16384) { src = w1; dst = w1q; off = idx * 4; }
    else             { src = w2; dst = w2q; off = (idx - 16384) * 4; }
    float4v f = *reinterpret_cast<const float4v*>(src + off);
    unsigned int dw = (unsigned int)(((int)f.x & 0xff) | (((int)f.y & 0xff) << 8) |
                                     (((int)f.z & 0xff) << 16) | (((int)f.w & 0xff) << 24));
    *reinterpret_cast<unsigned int*>(dst + off) = dw;
}

// Fused kernel: 8 waves/block (512 thr). Wave w owns rows [w*32, w*32+32) of
// both GEMMs; w1 fragments register-resident, w2 reloaded per strip (L2-hot)
// under the exchange barrier. (512,4): unified reg cap 128 -> target TWO
// blocks/CU co-resident (4 waves/SIMD). Grid 512, 4 strips of 32 cols each.
// 3 barriers/strip (merged max+sum exchange via LSE rescale).
__global__ __launch_bounds__(512, 4) void qdq_main(const float* __restrict__ x,
                                                   const unsigned char* __restrict__ w1q,
                                                   const unsigned char* __restrict__ w2q,
                                                   int* __restrict__ out) {
    __shared__ unsigned char xq[8192];   // [32 n][256 d] bytes, swizzled
    __shared__ unsigned char pq[8192];   // [32 n][256 k] bytes, swizzled
    __shared__ int   mb[8][32];          // per-wave column max
    __shared__ float sb[8][32];          // per-wave column partial sum (local max)

    const int tid  = threadIdx.x;
    const int wv   = tid >> 6;      // 0..7
    const int lane = tid & 63;
    const int c    = lane & 15;     // MFMA col-in-tile / A row-in-rowtile
    const int g    = lane >> 4;     // MFMA k-group 0..3

    // x-load / transpose roles: 8 rows x 32 cols (128B segments) per instr
    const int rsub = lane >> 3;     // 0..7
    const int cg   = lane & 7;      // float4 column group
    const int R    = rsub & 3;
    const unsigned int sel1 = (R & 1) ? 0x03070206u : 0x05010400u;
    const unsigned int sel2 = (R & 2) ? 0x07060302u : 0x01000504u;
    const int colsel = (0x3120 >> (R * 4)) & 0xF;   // {0,2,1,3}[R]
    const int n_t = cg * 4 + colsel;                // strip-local col 0..31
    const int qb  = rsub & 4;

    // ---- Persistent GEMM1 A-fragments: rows wv*32 + rt*16 + c, loaded ONCE ----
    int4v a1f[2][4];
    {
        const unsigned char* a1 = w1q + (size_t)(wv * 32 + c) * 256 + g * 16;
        #pragma unroll
        for (int rt = 0; rt < 2; ++rt)
            #pragma unroll
            for (int kk = 0; kk < 4; ++kk)
                a1f[rt][kk] = *reinterpret_cast<const int4v*>(a1 + rt * 4096 + kk * 64);
    }
    const unsigned char* a2 = w2q + (size_t)(wv * 32 + c) * 256 + g * 16;

    const int colstart = blockIdx.x * 128;
    const float* xpb = x + (size_t)(wv * 32 + rsub) * N_DIM + cg * 4;

    // ---- Prologue: strip-0 x loads (wave's rows wv*32 + i*8 + rsub) ----
    float4v raw[4];
    #pragma unroll
    for (int i = 0; i < 4; ++i)
        raw[i] = *reinterpret_cast<const float4v*>(xpb + (size_t)i * (8 * N_DIM) + colstart);

    const float C = 0.0056355275034725134f;   // SCORE_SCALE * log2(e)

    for (int it = 0; it < 4; ++it) {
        const int col0 = colstart + it * 32;

        // ---- 1. Quantize held x (magic fma); issue next strip's loads ----
        unsigned int Wq[4];
        #pragma unroll
        for (int i = 0; i < 4; ++i) Wq[i] = qpack(raw[i]);
        if (it < 3) {
            #pragma unroll
            for (int i = 0; i < 4; ++i)
                raw[i] = *reinterpret_cast<const float4v*>(
                    xpb + (size_t)i * (8 * N_DIM) + (col0 + 32));
        }

        // ---- 2. 4x4 byte transpose (partners lane^8, lane^16) -> xq ----
        #pragma unroll
        for (int i = 0; i < 4; ++i) {
            unsigned int t = (unsigned int)__shfl_xor((int)Wq[i], 8);
            unsigned int Q = __builtin_amdgcn_perm(t, Wq[i], sel1);
            unsigned int u = (unsigned int)__shfl_xor((int)Q, 16);
            unsigned int F = __builtin_amdgcn_perm(Q, u, sel2);
            const int dbase = wv * 32 + i * 8 + qb;
            *reinterpret_cast<unsigned int*>(
                xq + n_t * 256 + (dbase ^ ((n_t & 15) << 4))) = F;
        }
        __syncthreads();   // T: xq complete

        // ---- 3. B-fragments for GEMM1 (shared by all waves) ----
        int4v bq[2][4];
        #pragma unroll
        for (int t2 = 0; t2 < 2; ++t2)
            #pragma unroll
            for (int kk = 0; kk < 4; ++kk)
                bq[t2][kk] = *reinterpret_cast<const int4v*>(
                    xq + (t2 * 16 + c) * 256 + ((kk * 64 + g * 16) ^ (c << 4)));

        // ---- 4. GEMM1: 2 row-tiles x 2 col-tiles, A resident ----
        unsigned int scA[4], scB[4];
        int imA = -(1 << 30), imB = -(1 << 30);
        #pragma unroll
        for (int rt = 0; rt < 2; ++rt) {
            int4v accA = {0, 0, 0, 0}, accB = {0, 0, 0, 0};
            #pragma unroll
            for (int kk = 0; kk < 4; ++kk) {
                accA = __builtin_amdgcn_mfma_i32_16x16x64_i8(a1f[rt][kk], bq[0][kk], accA, 0, 0, 0);
                accB = __builtin_amdgcn_mfma_i32_16x16x64_i8(a1f[rt][kk], bq[1][kk], accB, 0, 0, 0);
            }
            {
                const int s0 = clamp16(accA[0]), s1 = clamp16(accA[1]);
                const int s2 = clamp16(accA[2]), s3 = clamp16(accA[3]);
                int m01 = s0 > s1 ? s0 : s1, m23 = s2 > s3 ? s2 : s3;
                int m = m01 > m23 ? m01 : m23;
                imA = imA > m ? imA : m;
                scA[2 * rt]     = (unsigned int)((s0 & 0xffff) | (s1 << 16));
                scA[2 * rt + 1] = (unsigned int)((s2 & 0xffff) | (s3 << 16));
            }
            {
                const int s0 = clamp16(accB[0]), s1 = clamp16(accB[1]);
                const int s2 = clamp16(accB[2]), s3 = clamp16(accB[3]);
                int m01 = s0 > s1 ? s0 : s1, m23 = s2 > s3 ? s2 : s3;
                int m = m01 > m23 ? m01 : m23;
                imB = imB > m ? imB : m;
                scB[2 * rt]     = (unsigned int)((s0 & 0xffff) | (s1 << 16));
                scB[2 * rt + 1] = (unsigned int)((s2 & 0xffff) | (s3 << 16));
            }
        }

        // ---- 5. Wave-level max; local-max exp sums (recomputed later); post ----
        {
            int o = __shfl_xor(imA, 16); imA = imA > o ? imA : o;
            o = __shfl_xor(imA, 32);     imA = imA > o ? imA : o;
            o = __shfl_xor(imB, 16);     imB = imB > o ? imB : o;
            o = __shfl_xor(imB, 32);     imB = imB > o ? imB : o;
        }
        if (g == 0) mb[wv][c] = imA;
        else if (g == 1) mb[wv][16 + c] = imB;
        float sA = 0.0f, sB = 0.0f;
        #pragma unroll
        for (int i = 0; i < 4; ++i) {
            sA += fexp2((float)((int)(short)(scA[i] & 0xffffu) - imA) * C);
            sA += fexp2((float)(((int)scA[i] >> 16) - imA) * C);
            sB += fexp2((float)((int)(short)(scB[i] & 0xffffu) - imB) * C);
            sB += fexp2((float)(((int)scB[i] >> 16) - imB) * C);
        }
        sA += __shfl_xor(sA, 16); sA += __shfl_xor(sA, 32);
        sB += __shfl_xor(sB, 16); sB += __shfl_xor(sB, 32);
        if (g == 0) sb[wv][c] = sA;
        else if (g == 1) sb[wv][16 + c] = sB;

        // ---- 6. Issue GEMM2 A-fragment loads (L2-hot; hidden under barrier) ----
        int4v a2f[2][4];
        #pragma unroll
        for (int rt = 0; rt < 2; ++rt)
            #pragma unroll
            for (int kk = 0; kk < 4; ++kk)
                a2f[rt][kk] = *reinterpret_cast<const int4v*>(a2 + rt * 4096 + kk * 64);
        __syncthreads();   // MS

        // ---- 7. Combine across waves (LSE rescale); fold into one scale ----
        int gmA = -(1 << 30), gmB = -(1 << 30);
        #pragma unroll
        for (int j = 0; j < 8; ++j) {
            int a = mb[j][c], b = mb[j][16 + c];
            gmA = gmA > a ? gmA : a;
            gmB = gmB > b ? gmB : b;
        }
        float gsA = 0.0f, gsB = 0.0f;
        #pragma unroll
        for (int j = 0; j < 8; ++j) {
            gsA += sb[j][c]      * fexp2((float)(mb[j][c] - gmA) * C);
            gsB += sb[j][16 + c] * fexp2((float)(mb[j][16 + c] - gmB) * C);
        }
        const float qsA = (2048.0f / gsA) * fexp2((float)(imA - gmA) * C);
        const float qsB = (2048.0f / gsB) * fexp2((float)(imB - gmB) * C);

        // ---- 8. Quantize probs (recompute exp2, magic fma pack) -> pq ----
        #pragma unroll
        for (int rt = 0; rt < 2; ++rt) {
            const int koff = wv * 32 + rt * 16 + g * 4;
            {
                float e0 = fexp2((float)((int)(short)(scA[2 * rt] & 0xffffu) - imA) * C);
                float e1 = fexp2((float)(((int)scA[2 * rt] >> 16) - imA) * C);
                float e2 = fexp2((float)((int)(short)(scA[2 * rt + 1] & 0xffffu) - imA) * C);
                float e3 = fexp2((float)(((int)scA[2 * rt + 1] >> 16) - imA) * C);
                *reinterpret_cast<unsigned int*>(
                    pq + c * 256 + (koff ^ (c << 4))) = qpack_probs(e0, e1, e2, e3, qsA);
            }
            {
                float e0 = fexp2((float)((int)(short)(scB[2 * rt] & 0xffffu) - imB) * C);
                float e1 = fexp2((float)(((int)scB[2 * rt] >> 16) - imB) * C);
                float e2 = fexp2((float)((int)(short)(scB[2 * rt + 1] & 0xffffu) - imB) * C);
                float e3 = fexp2((float)(((int)scB[2 * rt + 1] >> 16) - imB) * C);
                *reinterpret_cast<unsigned int*>(
                    pq + (16 + c) * 256 + (koff ^ (c << 4))) = qpack_probs(e0, e1, e2, e3, qsB);
            }
        }
        __syncthreads();   // P: pq complete

        // ---- 9. GEMM2: B from pq, A from per-strip regs; plain stores ----
        int4v b2[2][4];
        #pragma unroll
        for (int t2 = 0; t2 < 2; ++t2)
            #pragma unroll
            for (int kk = 0; kk < 4; ++kk)
                b2[t2][kk] = *reinterpret_cast<const int4v*>(
                    pq + (t2 * 16 + c) * 256 + ((kk * 64 + g * 16) ^ (c << 4)));

        #pragma unroll
        for (int rt = 0; rt < 2; ++rt) {
            int4v accA = {0, 0, 0, 0}, accB = {0, 0, 0, 0};
            #pragma unroll
            for (int kk = 0; kk < 4; ++kk) {
                accA = __builtin_amdgcn_mfma_i32_16x16x64_i8(a2f[rt][kk], b2[0][kk], accA, 0, 0, 0);
                accB = __builtin_amdgcn_mfma_i32_16x16x64_i8(a2f[rt][kk], b2[1][kk], accB, 0, 0, 0);
            }
            #pragma unroll
            for (int r = 0; r < 4; ++r) {
                const size_t rowoff =
                    (size_t)(wv * 32 + rt * 16 + g * 4 + r) * N_DIM + col0;
                out[rowoff + c]      = clamp16(accA[r]);
                out[rowoff + 16 + c] = clamp16(accB[r]);
            }
        }
    }
}

extern "C" void kernel_launch(void* const* d_in, const int* in_sizes, int n_in,
                              void* d_out, int out_size, void* d_ws, size_t ws_size,
                              hipStream_t stream) {
    const float* x  = (const float*)d_in[0];
    const float* w1 = (const float*)d_in[1];
    const float* w2 = (const float*)d_in[2];
    int* out = (int*)d_out;

    unsigned char* w1q = (unsigned char*)d_ws;
    unsigned char* w2q = w1q + 65536;

    quant_weights<<<128, 256, 0, stream>>>(w1, w2, w1q, w2q);
    qdq_main<<<512, 512, 0, stream>>>(x, w1q, w2q, out);
}

// Round 16
// 42.766 us; speedup vs baseline: 1.8993x; 1.8993x over previous
//
#include <hip/hip_runtime.h>

typedef int   int4v   __attribute__((ext_vector_type(4)));
typedef float float4v __attribute__((ext_vector_type(4)));

#define N_DIM 65536

// Magic-number round-half-even quantization (validated bit-exact in R15).
#define QMAGIC 12582912.0f            // 1.5 * 2^23
#define QHI    12583039.0f            // QMAGIC + 127
#define QLO    12582784.0f            // QMAGIC - 128

__device__ __forceinline__ int clamp16(int s) {
    s = s > 32767 ? 32767 : s;
    s = s < -32768 ? -32768 : s;
    return s;
}

__device__ __forceinline__ unsigned int pack_low_bytes(float f0, float f1,
                                                       float f2, float f3) {
    unsigned int p01 = __builtin_amdgcn_perm(__float_as_uint(f1),
                                             __float_as_uint(f0), 0x00000400u);
    unsigned int p23 = __builtin_amdgcn_perm(__float_as_uint(f3),
                                             __float_as_uint(f2), 0x00000400u);
    return __builtin_amdgcn_perm(p23, p01, 0x05040100u);
}

__device__ __forceinline__ unsigned int qpack(float4v v) {
    float f0 = fminf(fmaxf(fmaf(v.x, 16.0f, QMAGIC), QLO), QHI);
    float f1 = fminf(fmaxf(fmaf(v.y, 16.0f, QMAGIC), QLO), QHI);
    float f2 = fminf(fmaxf(fmaf(v.z, 16.0f, QMAGIC), QLO), QHI);
    float f3 = fminf(fmaxf(fmaf(v.w, 16.0f, QMAGIC), QLO), QHI);
    return pack_low_bytes(f0, f1, f2, f3);
}

__device__ __forceinline__ unsigned int qpack_probs(float e0, float e1,
                                                    float e2, float e3, float qs) {
    float f0 = fminf(fmaf(e0, qs, QMAGIC), QHI);
    float f1 = fminf(fmaf(e1, qs, QMAGIC), QHI);
    float f2 = fminf(fmaf(e2, qs, QMAGIC), QHI);
    float f3 = fminf(fmaf(e3, qs, QMAGIC), QHI);
    return pack_low_bytes(f0, f1, f2, f3);
}

__device__ __forceinline__ float fexp2(float a) {
    float r;
    asm("v_exp_f32 %0, %1" : "=v"(r) : "v"(a));
    return r;
}

// Pre-pass: w1/w2 are int-valued float32 in [-16,15]; pack to int8.
__global__ __launch_bounds__(256) void quant_weights(const float* __restrict__ w1,
                                                     const float* __restrict__ w2,
                                                     unsigned char* __restrict__ w1q,
                                                     unsigned char* __restrict__ w2q) {
    int idx = blockIdx.x * 256 + threadIdx.x;
    const float* src;
    unsigned char* dst;
    int off;
    if (idx < 16384) { src = w1; dst = w1q; off = idx * 4; }
    else             { src = w2; dst = w2q; off = (idx - 16384) * 4; }
    float4v f = *reinterpret_cast<const float4v*>(src + off);
    unsigned int dw = (unsigned int)(((int)f.x & 0xff) | (((int)f.y & 0xff) << 8) |
                                     (((int)f.z & 0xff) << 16) | (((int)f.w & 0xff) << 24));
    *reinterpret_cast<unsigned int*>(dst + off) = dw;
}

// Fused kernel: 8 waves/block (512 thr). Wave w owns rows [w*32, w*32+32).
// 64 COLUMNS per iteration (4 col-tiles): half the barriers of the 32-col
// version, 4 independent chains per phase. (512,2): reg cap 256, no spill;
// residency 1 block/CU (structural). Grid 256, 4 iters of 64 cols.
__global__ __launch_bounds__(512, 2) void qdq_main(const float* __restrict__ x,
                                                   const unsigned char* __restrict__ w1q,
                                                   const unsigned char* __restrict__ w2q,
                                                   int* __restrict__ out) {
    __shared__ unsigned char xq[16384];  // [64 n][256 d] bytes, swizzled
    __shared__ unsigned char pq[16384];  // [64 n][256 k] bytes, swizzled
    __shared__ int   mb[8][64];          // per-wave column max
    __shared__ float sb[8][64];          // per-wave column partial sum

    const int tid  = threadIdx.x;
    const int wv   = tid >> 6;      // 0..7
    const int lane = tid & 63;
    const int c    = lane & 15;     // MFMA col-in-tile / A row-in-rowtile
    const int g    = lane >> 4;     // MFMA k-group 0..3

    const int rsub = lane >> 3;     // 0..7
    const int cg   = lane & 7;      // float4 column group (32-col half)
    const int R    = rsub & 3;
    const unsigned int sel1 = (R & 1) ? 0x03070206u : 0x05010400u;
    const unsigned int sel2 = (R & 2) ? 0x07060302u : 0x01000504u;
    const int colsel = (0x3120 >> (R * 4)) & 0xF;   // {0,2,1,3}[R]
    const int n_t = cg * 4 + colsel;                // col 0..31 within half
    const int qb  = rsub & 4;

    // ---- Persistent GEMM1 A-fragments ----
    int4v a1f[2][4];
    {
        const unsigned char* a1 = w1q + (size_t)(wv * 32 + c) * 256 + g * 16;
        #pragma unroll
        for (int rt = 0; rt < 2; ++rt)
            #pragma unroll
            for (int kk = 0; kk < 4; ++kk)
                a1f[rt][kk] = *reinterpret_cast<const int4v*>(a1 + rt * 4096 + kk * 64);
    }
    const unsigned char* a2 = w2q + (size_t)(wv * 32 + c) * 256 + g * 16;

    const int colstart = blockIdx.x * 256;
    const float* xpb = x + (size_t)(wv * 32 + rsub) * N_DIM + cg * 4;

    // ---- Prologue: iter-0 x loads (8 rows x 64 cols per wave) ----
    float4v raw[8];
    #pragma unroll
    for (int i = 0; i < 4; ++i) {
        raw[2 * i]     = *reinterpret_cast<const float4v*>(
            xpb + (size_t)i * (8 * N_DIM) + colstart);
        raw[2 * i + 1] = *reinterpret_cast<const float4v*>(
            xpb + (size_t)i * (8 * N_DIM) + colstart + 32);
    }

    const float C = 0.0056355275034725134f;   // SCORE_SCALE * log2(e)

    for (int it = 0; it < 4; ++it) {
        const int col0 = colstart + it * 64;

        // ---- 1. Quantize held x; then issue next iter's loads (raw dead) ----
        unsigned int Wq[8];
        #pragma unroll
        for (int i = 0; i < 8; ++i) Wq[i] = qpack(raw[i]);
        if (it < 3) {
            #pragma unroll
            for (int i = 0; i < 4; ++i) {
                raw[2 * i]     = *reinterpret_cast<const float4v*>(
                    xpb + (size_t)i * (8 * N_DIM) + col0 + 64);
                raw[2 * i + 1] = *reinterpret_cast<const float4v*>(
                    xpb + (size_t)i * (8 * N_DIM) + col0 + 96);
            }
        }

        // ---- 2. 4x4 byte transpose -> xq (both 32-col halves) ----
        #pragma unroll
        for (int i = 0; i < 4; ++i) {
            #pragma unroll
            for (int h = 0; h < 2; ++h) {
                unsigned int Wv = Wq[2 * i + h];
                unsigned int t = (unsigned int)__shfl_xor((int)Wv, 8);
                unsigned int Q = __builtin_amdgcn_perm(t, Wv, sel1);
                unsigned int u = (unsigned int)__shfl_xor((int)Q, 16);
                unsigned int F = __builtin_amdgcn_perm(Q, u, sel2);
                const int n_loc = h * 32 + n_t;
                const int dbase = wv * 32 + i * 8 + qb;
                *reinterpret_cast<unsigned int*>(
                    xq + n_loc * 256 + (dbase ^ ((n_loc & 15) << 4))) = F;
            }
        }
        __syncthreads();   // T: xq complete

        // ---- 3. GEMM1: 4 col-tiles x 2 row-tiles, A resident, bq transient ----
        unsigned int sc[4][4];
        int im0, im1, im2, im3;
        #pragma unroll
        for (int t2 = 0; t2 < 4; ++t2) {
            int4v bq[4];
            #pragma unroll
            for (int kk = 0; kk < 4; ++kk)
                bq[kk] = *reinterpret_cast<const int4v*>(
                    xq + (t2 * 16 + c) * 256 + ((kk * 64 + g * 16) ^ (c << 4)));
            int imt = -(1 << 30);
            #pragma unroll
            for (int rt = 0; rt < 2; ++rt) {
                int4v acc = {0, 0, 0, 0};
                #pragma unroll
                for (int kk = 0; kk < 4; ++kk)
                    acc = __builtin_amdgcn_mfma_i32_16x16x64_i8(a1f[rt][kk], bq[kk], acc, 0, 0, 0);
                const int s0 = clamp16(acc[0]), s1 = clamp16(acc[1]);
                const int s2 = clamp16(acc[2]), s3 = clamp16(acc[3]);
                int m01 = s0 > s1 ? s0 : s1, m23 = s2 > s3 ? s2 : s3;
                int m = m01 > m23 ? m01 : m23;
                imt = imt > m ? imt : m;
                sc[t2][2 * rt]     = (unsigned int)((s0 & 0xffff) | (s1 << 16));
                sc[t2][2 * rt + 1] = (unsigned int)((s2 & 0xffff) | (s3 << 16));
            }
            if (t2 == 0) im0 = imt;
            else if (t2 == 1) im1 = imt;
            else if (t2 == 2) im2 = imt;
            else im3 = imt;
        }

        // ---- 4. Wave-level max + local sums (4 independent chains) ----
        {
            int o;
            o = __shfl_xor(im0, 16); im0 = im0 > o ? im0 : o;
            o = __shfl_xor(im0, 32); im0 = im0 > o ? im0 : o;
            o = __shfl_xor(im1, 16); im1 = im1 > o ? im1 : o;
            o = __shfl_xor(im1, 32); im1 = im1 > o ? im1 : o;
            o = __shfl_xor(im2, 16); im2 = im2 > o ? im2 : o;
            o = __shfl_xor(im2, 32); im2 = im2 > o ? im2 : o;
            o = __shfl_xor(im3, 16); im3 = im3 > o ? im3 : o;
            o = __shfl_xor(im3, 32); im3 = im3 > o ? im3 : o;
        }
        float s0 = 0.0f, s1 = 0.0f, s2 = 0.0f, s3 = 0.0f;
        #pragma unroll
        for (int i = 0; i < 4; ++i) {
            s0 += fexp2((float)((int)(short)(sc[0][i] & 0xffffu) - im0) * C);
            s0 += fexp2((float)(((int)sc[0][i] >> 16) - im0) * C);
            s1 += fexp2((float)((int)(short)(sc[1][i] & 0xffffu) - im1) * C);
            s1 += fexp2((float)(((int)sc[1][i] >> 16) - im1) * C);
            s2 += fexp2((float)((int)(short)(sc[2][i] & 0xffffu) - im2) * C);
            s2 += fexp2((float)(((int)sc[2][i] >> 16) - im2) * C);
            s3 += fexp2((float)((int)(short)(sc[3][i] & 0xffffu) - im3) * C);
            s3 += fexp2((float)(((int)sc[3][i] >> 16) - im3) * C);
        }
        s0 += __shfl_xor(s0, 16); s0 += __shfl_xor(s0, 32);
        s1 += __shfl_xor(s1, 16); s1 += __shfl_xor(s1, 32);
        s2 += __shfl_xor(s2, 16); s2 += __shfl_xor(s2, 32);
        s3 += __shfl_xor(s3, 16); s3 += __shfl_xor(s3, 32);
        // Lane's k-group g posts tile g: one unmasked store per lane.
        {
            int imv  = (g == 0) ? im0 : (g == 1) ? im1 : (g == 2) ? im2 : im3;
            float sv = (g == 0) ? s0  : (g == 1) ? s1  : (g == 2) ? s2  : s3;
            mb[wv][g * 16 + c] = imv;
            sb[wv][g * 16 + c] = sv;
        }

        // ---- 5. Issue GEMM2 A-fragment loads (L2-hot; hidden under barrier) ----
        int4v a2f[2][4];
        #pragma unroll
        for (int rt = 0; rt < 2; ++rt)
            #pragma unroll
            for (int kk = 0; kk < 4; ++kk)
                a2f[rt][kk] = *reinterpret_cast<const int4v*>(a2 + rt * 4096 + kk * 64);
        __syncthreads();   // MS

        // ---- 6. Combine across waves (LSE rescale), fold per-tile scale ----
        float qs0, qs1, qs2, qs3;
        #pragma unroll
        for (int t2 = 0; t2 < 4; ++t2) {
            const int imt = (t2 == 0) ? im0 : (t2 == 1) ? im1 : (t2 == 2) ? im2 : im3;
            int gm = -(1 << 30);
            #pragma unroll
            for (int j = 0; j < 8; ++j) {
                int a = mb[j][t2 * 16 + c];
                gm = gm > a ? gm : a;
            }
            float gs = 0.0f;
            #pragma unroll
            for (int j = 0; j < 8; ++j)
                gs += sb[j][t2 * 16 + c] * fexp2((float)(mb[j][t2 * 16 + c] - gm) * C);
            const float qs = (2048.0f / gs) * fexp2((float)(imt - gm) * C);
            if (t2 == 0) qs0 = qs;
            else if (t2 == 1) qs1 = qs;
            else if (t2 == 2) qs2 = qs;
            else qs3 = qs;
        }

        // ---- 7. Quantize probs (recompute exp2, magic pack) -> pq ----
        #pragma unroll
        for (int t2 = 0; t2 < 4; ++t2) {
            const int imt = (t2 == 0) ? im0 : (t2 == 1) ? im1 : (t2 == 2) ? im2 : im3;
            const float qs = (t2 == 0) ? qs0 : (t2 == 1) ? qs1 : (t2 == 2) ? qs2 : qs3;
            #pragma unroll
            for (int rt = 0; rt < 2; ++rt) {
                const int koff = wv * 32 + rt * 16 + g * 4;
                float e0 = fexp2((float)((int)(short)(sc[t2][2 * rt] & 0xffffu) - imt) * C);
                float e1 = fexp2((float)(((int)sc[t2][2 * rt] >> 16) - imt) * C);
                float e2 = fexp2((float)((int)(short)(sc[t2][2 * rt + 1] & 0xffffu) - imt) * C);
                float e3 = fexp2((float)(((int)sc[t2][2 * rt + 1] >> 16) - imt) * C);
                *reinterpret_cast<unsigned int*>(
                    pq + (t2 * 16 + c) * 256 + (koff ^ (c << 4))) =
                    qpack_probs(e0, e1, e2, e3, qs);
            }
        }
        __syncthreads();   // P: pq complete

        // ---- 8. GEMM2: 4 col-tiles, b2 transient; direct stores ----
        #pragma unroll
        for (int t2 = 0; t2 < 4; ++t2) {
            int4v b2[4];
            #pragma unroll
            for (int kk = 0; kk < 4; ++kk)
                b2[kk] = *reinterpret_cast<const int4v*>(
                    pq + (t2 * 16 + c) * 256 + ((kk * 64 + g * 16) ^ (c << 4)));
            #pragma unroll
            for (int rt = 0; rt < 2; ++rt) {
                int4v acc = {0, 0, 0, 0};
                #pragma unroll
                for (int kk = 0; kk < 4; ++kk)
                    acc = __builtin_amdgcn_mfma_i32_16x16x64_i8(a2f[rt][kk], b2[kk], acc, 0, 0, 0);
                #pragma unroll
                for (int r = 0; r < 4; ++r) {
                    const size_t rowoff =
                        (size_t)(wv * 32 + rt * 16 + g * 4 + r) * N_DIM + col0;
                    out[rowoff + t2 * 16 + c] = clamp16(acc[r]);
                }
            }
        }
    }
}

extern "C" void kernel_launch(void* const* d_in, const int* in_sizes, int n_in,
                              void* d_out, int out_size, void* d_ws, size_t ws_size,
                              hipStream_t stream) {
    const float* x  = (const float*)d_in[0];
    const float* w1 = (const float*)d_in[1];
    const float* w2 = (const float*)d_in[2];
    int* out = (int*)d_out;

    unsigned char* w1q = (unsigned char*)d_ws;
    unsigned char* w2q = w1q + 65536;

    quant_weights<<<128, 256, 0, stream>>>(w1, w2, w1q, w2q);
    qdq_main<<<256, 512, 0, stream>>>(x, w1q, w2q, out);
}